// Round 13
// baseline (1001.142 us; speedup 1.0000x reference)
//
#include <hip/hip_runtime.h>
#include <float.h>

constexpr int NB   = 8;      // batches
constexpr int NP   = 2048;   // points per batch
constexpr int BN   = NB * NP;
constexpr int KNN  = 20;     // neighbors
constexpr int FSTR = 512;    // feats row stride (64+64+128+256)

typedef short short8 __attribute__((ext_vector_type(8)));
typedef float f32x4  __attribute__((ext_vector_type(4)));

__device__ __forceinline__ unsigned f2bf_rne(float x) {
    unsigned u = __float_as_uint(x);
    unsigned r = (u >> 16) & 1;
    return (u + 0x7fffu + r) >> 16;
}
__device__ __forceinline__ float bf2f(unsigned h) { return __uint_as_float(h << 16); }

// ---------------------------------------------------------------- sq = |h|^2
template<int C>
__global__ __launch_bounds__(256) void sq_kernel(const float* __restrict__ h,
                                                 int istr,
                                                 float* __restrict__ sq) {
    int i = blockIdx.x * 256 + threadIdx.x;
    if (i >= BN) return;
    const float* p = h + (size_t)i * istr;
    float s = 0.f;
    #pragma unroll
    for (int c = 0; c < C; ++c) { float v = p[c]; s += v * v; }
    sq[i] = s;
}

// ---------------------------------------------------------------- kNN top-20 (C=3 path)
template<int C>
__global__ __launch_bounds__(256) void knn_kernel(const float* __restrict__ h,
                                                  int istr,
                                                  const float* __restrict__ sq,
                                                  int* __restrict__ knn_idx) {
    constexpr int GI = 4;
    __shared__ float negd[GI][NP];          // 32 KB
    const int t    = threadIdx.x;
    const int r0   = blockIdx.x * GI;
    const int base = (r0 >> 11) << 11;

    float hi[GI][3], sqi[GI];
    #pragma unroll
    for (int g = 0; g < GI; ++g) {
        const float* p = h + (size_t)(r0 + g) * istr;
        hi[g][0] = p[0]; hi[g][1] = p[1]; hi[g][2] = p[2];
        sqi[g] = sq[r0 + g];
    }
    for (int j = t; j < NP; j += 256) {
        const float* pj = h + (size_t)(base + j) * istr;
        float x0 = pj[0], x1 = pj[1], x2 = pj[2];
        float sqj = sq[base + j];
        #pragma unroll
        for (int g = 0; g < GI; ++g) {
            float d = hi[g][0]*x0 + hi[g][1]*x1 + hi[g][2]*x2;
            negd[g][j] = 2.f * d - sqi[g] - sqj;
        }
    }
    __syncthreads();

    const int w = t >> 6;
    const int l = t & 63;
    const float* row = &negd[w][0];
    float v[32];
    #pragma unroll
    for (int u = 0; u < 32; ++u) v[u] = row[l + 64 * u];
    float m0 = v[0], m1 = v[16];
    int   u0 = 0,    u1 = 16;
    #pragma unroll
    for (int u = 1; u < 16; ++u)  { if (v[u] > m0) { m0 = v[u]; u0 = u; } }
    #pragma unroll
    for (int u = 17; u < 32; ++u) { if (v[u] > m1) { m1 = v[u]; u1 = u; } }

    int* out = knn_idx + (size_t)(r0 + w) * KNN;
    for (int it = 0; it < KNN; ++it) {
        float bv; int bu;
        if (m0 >= m1) { bv = m0; bu = u0; } else { bv = m1; bu = u1; }
        int bj = l + (bu << 6);
        #pragma unroll
        for (int off = 1; off < 64; off <<= 1) {
            float ov = __shfl_xor(bv, off);
            int   oj = __shfl_xor(bj, off);
            if (ov > bv || (ov == bv && oj < bj)) { bv = ov; bj = oj; }
        }
        if (l == 0) out[it] = bj;
        const int  ur  = bj >> 6;
        const bool own = ((bj & 63) == l);
        if (ur < 16) {
            #pragma unroll
            for (int u = 0; u < 16; ++u)
                if (own && u == ur) v[u] = -FLT_MAX;
            m0 = v[0]; u0 = 0;
            #pragma unroll
            for (int u = 1; u < 16; ++u) if (v[u] > m0) { m0 = v[u]; u0 = u; }
        } else {
            #pragma unroll
            for (int u = 16; u < 32; ++u)
                if (own && u == ur) v[u] = -FLT_MAX;
            m1 = v[16]; u1 = 16;
            #pragma unroll
            for (int u = 17; u < 32; ++u) if (v[u] > m1) { m1 = v[u]; u1 = u; }
        }
    }
}

// ---------------------------------------------------------------- H hi/lo plane prep
__global__ __launch_bounds__(256) void hprep_kernel(const float* __restrict__ h, int istr,
                                                    int cin, int total,
                                                    short* __restrict__ hhi,
                                                    short* __restrict__ hlo) {
    int e = blockIdx.x * 256 + threadIdx.x;
    if (e >= total) return;
    int r = e / cin, c = e - r * cin;
    float v = h[(size_t)r * istr + c];
    unsigned hh = f2bf_rne(v);
    unsigned ll = __float_as_uint(v - bf2f(hh)) >> 16;
    hhi[e] = (short)hh;
    hlo[e] = (short)ll;
}

// ---------------------------------------------------------------- Gram via MFMA (bf16 hi/lo, 3-term, direct global A/B)
template<int KC>    // K = KC*64 = C
__global__ __launch_bounds__(256) void gram_mfma(const short* __restrict__ hhi,
                                                 const short* __restrict__ hlo,
                                                 const float* __restrict__ sq,
                                                 int g0,
                                                 float* __restrict__ gram) {
    constexpr int C = KC * 64;
    const int t   = threadIdx.x;
    const int bx  = blockIdx.x;
    const int ct  = blockIdx.y;
    const int big = bx >> 5, rt = bx & 31;
    const int bbase = g0 + big * NP;               // batch base (global row)
    const int row0g = bbase + rt * 64;
    const int l = t & 63, w = t >> 6, g = l >> 4, cl = l & 15;

    f32x4 acc[4][2];
    #pragma unroll
    for (int mt = 0; mt < 4; ++mt)
        #pragma unroll
        for (int nt = 0; nt < 2; ++nt)
            acc[mt][nt] = (f32x4){0.f, 0.f, 0.f, 0.f};

    #pragma unroll 1
    for (int kc = 0; kc < KC; ++kc) {
        #pragma unroll
        for (int ks = 0; ks < 2; ++ks) {
            const int k0 = kc * 64 + ks * 32 + g * 8;
            short8 ah[4], al[4], bh[2], bl[2];
            #pragma unroll
            for (int mt = 0; mt < 4; ++mt) {
                size_t aoff = (size_t)(row0g + mt * 16 + cl) * C + k0;
                ah[mt] = *(const short8*)(hhi + aoff);
                al[mt] = *(const short8*)(hlo + aoff);
            }
            #pragma unroll
            for (int nt = 0; nt < 2; ++nt) {
                int col = ct * 128 + (w * 2 + nt) * 16 + cl;
                size_t boff = (size_t)(bbase + col) * C + k0;
                bh[nt] = *(const short8*)(hhi + boff);
                bl[nt] = *(const short8*)(hlo + boff);
            }
            #pragma unroll
            for (int mt = 0; mt < 4; ++mt)
                #pragma unroll
                for (int nt = 0; nt < 2; ++nt) {
                    acc[mt][nt] = __builtin_amdgcn_mfma_f32_16x16x32_bf16(
                        ah[mt], bh[nt], acc[mt][nt], 0, 0, 0);
                    acc[mt][nt] = __builtin_amdgcn_mfma_f32_16x16x32_bf16(
                        ah[mt], bl[nt], acc[mt][nt], 0, 0, 0);
                    acc[mt][nt] = __builtin_amdgcn_mfma_f32_16x16x32_bf16(
                        al[mt], bh[nt], acc[mt][nt], 0, 0, 0);
                }
        }
    }

    // epilogue: negd = 2*acc - sq_r - sq_c
    #pragma unroll
    for (int nt = 0; nt < 2; ++nt) {
        int col = ct * 128 + (w * 2 + nt) * 16 + cl;
        float sqc = sq[bbase + col];
        #pragma unroll
        for (int mt = 0; mt < 4; ++mt) {
            #pragma unroll
            for (int j = 0; j < 4; ++j) {
                int rl = rt * 64 + mt * 16 + g * 4 + j;
                float val = 2.f * acc[mt][nt][j] - sq[bbase + rl] - sqc;
                gram[(size_t)(big * NP + rl) * NP + col] = val;
            }
        }
    }
}

// ---------------------------------------------------------------- top-20 selection from gram rows
__global__ __launch_bounds__(512) void select_topk(const float* __restrict__ gram,
                                                   int g0,
                                                   int* __restrict__ knn_idx) {
    const int t = threadIdx.x, w = t >> 6, l = t & 63;
    const int rlocal = blockIdx.x * 8 + w;
    const float* row = gram + (size_t)rlocal * NP;

    float v[32];
    #pragma unroll
    for (int u = 0; u < 32; ++u) v[u] = row[l + 64 * u];
    float m0 = v[0], m1 = v[16];
    int   u0 = 0,    u1 = 16;
    #pragma unroll
    for (int u = 1; u < 16; ++u)  { if (v[u] > m0) { m0 = v[u]; u0 = u; } }
    #pragma unroll
    for (int u = 17; u < 32; ++u) { if (v[u] > m1) { m1 = v[u]; u1 = u; } }

    int* out = knn_idx + (size_t)(g0 + rlocal) * KNN;
    for (int it = 0; it < KNN; ++it) {
        float bv; int bu;
        if (m0 >= m1) { bv = m0; bu = u0; } else { bv = m1; bu = u1; }
        int bj = l + (bu << 6);
        #pragma unroll
        for (int off = 1; off < 64; off <<= 1) {
            float ov = __shfl_xor(bv, off);
            int   oj = __shfl_xor(bj, off);
            if (ov > bv || (ov == bv && oj < bj)) { bv = ov; bj = oj; }
        }
        if (l == 0) out[it] = bj;
        const int  ur  = bj >> 6;
        const bool own = ((bj & 63) == l);
        if (ur < 16) {
            #pragma unroll
            for (int u = 0; u < 16; ++u)
                if (own && u == ur) v[u] = -FLT_MAX;
            m0 = v[0]; u0 = 0;
            #pragma unroll
            for (int u = 1; u < 16; ++u) if (v[u] > m0) { m0 = v[u]; u0 = u; }
        } else {
            #pragma unroll
            for (int u = 16; u < 32; ++u)
                if (own && u == ur) v[u] = -FLT_MAX;
            m1 = v[16]; u1 = 16;
            #pragma unroll
            for (int u = 17; u < 32; ++u) if (v[u] > m1) { m1 = v[u]; u1 = u; }
        }
    }
}

// ---------------------------------------------------------------- U/V' hi-lo prep
__global__ __launch_bounds__(256) void uvprep_kernel(const float* __restrict__ W,
                                                     int cin, int cout,
                                                     short* __restrict__ bhi,
                                                     short* __restrict__ blo) {
    int e = blockIdx.x * 256 + threadIdx.x;
    if (e >= cout * cin) return;
    int o = e / cin, c = e - o * cin;
    float u  = W[(size_t)o * (2 * cin) + c];
    float vv = W[(size_t)o * (2 * cin) + cin + c];
    float vp = vv - u;
    unsigned hu = f2bf_rne(u);
    unsigned lu = __float_as_uint(u - bf2f(hu)) >> 16;
    unsigned hv = f2bf_rne(vp);
    unsigned lv = __float_as_uint(vp - bf2f(hv)) >> 16;
    bhi[(size_t)o * cin + c] = (short)hu;
    blo[(size_t)o * cin + c] = (short)lu;
    bhi[(size_t)(cout + o) * cin + c] = (short)hv;
    blo[(size_t)(cout + o) * cin + c] = (short)lv;
}

// ---------------------------------------------------------------- Wf hi/lo prep (flat)
__global__ __launch_bounds__(256) void wfprep_kernel(const float* __restrict__ Wf,
                                                     short* __restrict__ whi,
                                                     short* __restrict__ wlo) {
    int e = blockIdx.x * 256 + threadIdx.x;
    float v = Wf[e];
    unsigned h = f2bf_rne(v);
    unsigned lo = __float_as_uint(v - bf2f(h)) >> 16;
    whi[e] = (short)h;
    wlo[e] = (short)lo;
}

// ---------------------------------------------------------------- node GEMM via MFMA (bf16 hi/lo, 3-term, direct global A/B)
template<int KC>
__global__ __launch_bounds__(256) void gemm_node(const short* __restrict__ ahi,
                                                 const short* __restrict__ alo,
                                                 const short* __restrict__ bhi_,
                                                 const short* __restrict__ blo_,
                                                 int nstr,
                                                 float* __restrict__ out) {
    constexpr int C = KC * 64;
    const int t    = threadIdx.x;
    const int mb   = blockIdx.x;
    const int ny   = blockIdx.y;
    const int row0 = mb * 64;
    const int l = t & 63, w = t >> 6, g = l >> 4, cl = l & 15;

    f32x4 acc[4][2];
    #pragma unroll
    for (int mt = 0; mt < 4; ++mt)
        #pragma unroll
        for (int nt = 0; nt < 2; ++nt)
            acc[mt][nt] = (f32x4){0.f, 0.f, 0.f, 0.f};

    #pragma unroll 1
    for (int kc = 0; kc < KC; ++kc) {
        #pragma unroll
        for (int ks = 0; ks < 2; ++ks) {
            const int k0 = kc * 64 + ks * 32 + g * 8;
            short8 ah[4], al[4], bh[2], bl[2];
            #pragma unroll
            for (int mt = 0; mt < 4; ++mt) {
                size_t aoff = (size_t)(row0 + mt * 16 + cl) * C + k0;
                ah[mt] = *(const short8*)(ahi + aoff);
                al[mt] = *(const short8*)(alo + aoff);
            }
            #pragma unroll
            for (int nt = 0; nt < 2; ++nt) {
                int o = ny * 128 + (w * 2 + nt) * 16 + cl;
                size_t boff = (size_t)o * C + k0;
                bh[nt] = *(const short8*)(bhi_ + boff);
                bl[nt] = *(const short8*)(blo_ + boff);
            }
            #pragma unroll
            for (int mt = 0; mt < 4; ++mt)
                #pragma unroll
                for (int nt = 0; nt < 2; ++nt) {
                    acc[mt][nt] = __builtin_amdgcn_mfma_f32_16x16x32_bf16(
                        ah[mt], bh[nt], acc[mt][nt], 0, 0, 0);
                    acc[mt][nt] = __builtin_amdgcn_mfma_f32_16x16x32_bf16(
                        ah[mt], bl[nt], acc[mt][nt], 0, 0, 0);
                    acc[mt][nt] = __builtin_amdgcn_mfma_f32_16x16x32_bf16(
                        al[mt], bh[nt], acc[mt][nt], 0, 0, 0);
                }
        }
    }

    #pragma unroll
    for (int nt = 0; nt < 2; ++nt) {
        int col = ny * 128 + (w * 2 + nt) * 16 + cl;
        #pragma unroll
        for (int mt = 0; mt < 4; ++mt) {
            #pragma unroll
            for (int j = 0; j < 4; ++j) {
                int row = row0 + mt * 16 + g * 4 + j;
                out[(size_t)row * nstr + col] = acc[mt][nt][j];
            }
        }
    }
}

// ---------------------------------------------------------------- gather-max epilogue
template<int COUT, int PPB>
__global__ __launch_bounds__(256) void gather_max(const float* __restrict__ GC, int nstr,
                                                  const int* __restrict__ knn_idx,
                                                  const float* __restrict__ bias,
                                                  float* __restrict__ hout) {
    static_assert(COUT * PPB == 256, "block 256");
    const int t  = threadIdx.x;
    const int pl = t / COUT;
    const int o  = t - pl * COUT;
    const int p  = blockIdx.x * PPB + pl;
    const int base = (p >> 11) << 11;
    const int* jrow = knn_idx + (size_t)p * KNN;

    float mx = -FLT_MAX;
    #pragma unroll
    for (int k = 0; k < KNN; ++k) {
        int j = jrow[k];
        mx = fmaxf(mx, GC[(size_t)(base + j) * nstr + o]);
    }
    float val = mx + GC[(size_t)p * nstr + COUT + o] + bias[o];
    val = val > 0.f ? val : 0.2f * val;
    hout[(size_t)p * FSTR + o] = val;
}

// ---------------------------------------------------------------- EdgeConv L0 (CIN=3, fp32 VALU)
template<int CIN, int COUT, int PPB>
__global__ __launch_bounds__(256) void edge_kernel(const float* __restrict__ hin,
                                                   int istr,
                                                   const float* __restrict__ W,
                                                   const float* __restrict__ bias,
                                                   const int* __restrict__ knn_idx,
                                                   float* __restrict__ hout) {
    constexpr int TPP = COUT / 2;
    static_assert(PPB * TPP == 256, "block must be 256 threads");
    __shared__ float diff[PPB][KNN][CIN];
    __shared__ float hi[PPB][CIN];
    __shared__ int   nj[PPB][KNN];

    const int t    = threadIdx.x;
    const int r0   = blockIdx.x * PPB;
    const int base = (r0 >> 11) << 11;

    for (int e = t; e < PPB * KNN; e += 256) {
        int p = e / KNN, kk = e - p * KNN;
        nj[p][kk] = knn_idx[(size_t)(r0 + p) * KNN + kk];
    }
    for (int e = t; e < PPB * CIN; e += 256) {
        int p = e / CIN, c = e - p * CIN;
        hi[p][c] = hin[(size_t)(r0 + p) * istr + c];
    }
    __syncthreads();
    for (int e = t; e < PPB * KNN * CIN; e += 256) {
        int p  = e / (KNN * CIN);
        int rm = e - p * (KNN * CIN);
        int kk = rm / CIN, c = rm - kk * CIN;
        diff[p][kk][c] = hin[(size_t)(base + nj[p][kk]) * istr + c] - hi[p][c];
    }
    __syncthreads();

    const int p  = t / TPP;
    const int oo = t - p * TPP;
    const float* W0 = W + (size_t)oo * (2 * CIN);
    const float* W1 = W + (size_t)(oo + TPP) * (2 * CIN);

    float ctr0 = bias[oo], ctr1 = bias[oo + TPP];
    float acc[2][KNN];
    #pragma unroll
    for (int kk = 0; kk < KNN; ++kk) { acc[0][kk] = 0.f; acc[1][kk] = 0.f; }

    for (int c = 0; c < CIN; ++c) {
        float hv = hi[p][c];
        ctr0 += W0[CIN + c] * hv;
        ctr1 += W1[CIN + c] * hv;
    }
    for (int c = 0; c < CIN; ++c) {
        float w0 = W0[c], w1 = W1[c];
        #pragma unroll
        for (int kk = 0; kk < KNN; ++kk) {
            float d = diff[p][kk][c];
            acc[0][kk] += w0 * d;
            acc[1][kk] += w1 * d;
        }
    }

    float m0 = -FLT_MAX, m1 = -FLT_MAX;
    #pragma unroll
    for (int kk = 0; kk < KNN; ++kk) {
        m0 = fmaxf(m0, acc[0][kk] + ctr0);
        m1 = fmaxf(m1, acc[1][kk] + ctr1);
    }
    float r0v = m0 > 0.f ? m0 : 0.2f * m0;
    float r1v = m1 > 0.f ? m1 : 0.2f * m1;
    hout[(size_t)(r0 + p) * FSTR + oo]       = r0v;
    hout[(size_t)(r0 + p) * FSTR + oo + TPP] = r1v;
}

// ---------------------------------------------------------------- final GEMM via MFMA (bf16 hi/lo, 3-term, direct global A/B) + col-max
__global__ __launch_bounds__(256) void final_mfma(const short* __restrict__ fhi,
                                                  const short* __restrict__ flo,
                                                  const short* __restrict__ wfhi,
                                                  const short* __restrict__ wflo,
                                                  float* __restrict__ partial) {
    const int t    = threadIdx.x;
    const int mb   = blockIdx.x;
    const int ny   = blockIdx.y;
    const int row0 = mb * 64;
    const int l = t & 63, w = t >> 6, g = l >> 4, cl = l & 15;

    f32x4 acc[4][2];
    #pragma unroll
    for (int mt = 0; mt < 4; ++mt)
        #pragma unroll
        for (int nt = 0; nt < 2; ++nt)
            acc[mt][nt] = (f32x4){0.f, 0.f, 0.f, 0.f};

    #pragma unroll 1
    for (int kc = 0; kc < 8; ++kc) {
        #pragma unroll
        for (int ks = 0; ks < 2; ++ks) {
            const int k0 = kc * 64 + ks * 32 + g * 8;
            short8 ah[4], al[4], bh[2], bl[2];
            #pragma unroll
            for (int mt = 0; mt < 4; ++mt) {
                size_t aoff = (size_t)(row0 + mt * 16 + cl) * 512 + k0;
                ah[mt] = *(const short8*)(fhi + aoff);
                al[mt] = *(const short8*)(flo + aoff);
            }
            #pragma unroll
            for (int nt = 0; nt < 2; ++nt) {
                int o = ny * 128 + (w * 2 + nt) * 16 + cl;
                size_t boff = (size_t)o * 512 + k0;
                bh[nt] = *(const short8*)(wfhi + boff);
                bl[nt] = *(const short8*)(wflo + boff);
            }
            #pragma unroll
            for (int mt = 0; mt < 4; ++mt)
                #pragma unroll
                for (int nt = 0; nt < 2; ++nt) {
                    acc[mt][nt] = __builtin_amdgcn_mfma_f32_16x16x32_bf16(
                        ah[mt], bh[nt], acc[mt][nt], 0, 0, 0);
                    acc[mt][nt] = __builtin_amdgcn_mfma_f32_16x16x32_bf16(
                        ah[mt], bl[nt], acc[mt][nt], 0, 0, 0);
                    acc[mt][nt] = __builtin_amdgcn_mfma_f32_16x16x32_bf16(
                        al[mt], bh[nt], acc[mt][nt], 0, 0, 0);
                }
        }
    }

    #pragma unroll
    for (int nt = 0; nt < 2; ++nt) {
        float pm = -FLT_MAX;
        #pragma unroll
        for (int mt = 0; mt < 4; ++mt) {
            f32x4 v = acc[mt][nt];
            pm = fmaxf(pm, fmaxf(fmaxf(v[0], v[1]), fmaxf(v[2], v[3])));
        }
        pm = fmaxf(pm, __shfl_xor(pm, 16));
        pm = fmaxf(pm, __shfl_xor(pm, 32));
        if (g == 0) {
            int col = ny * 128 + (w * 2 + nt) * 16 + cl;
            partial[(size_t)mb * 1024 + col] = pm;
        }
    }
}

__global__ __launch_bounds__(256) void final_reduce(const float* __restrict__ partial,
                                                    const float* __restrict__ bf,
                                                    float* __restrict__ out) {
    int g = blockIdx.x * 256 + threadIdx.x;
    int b = g >> 10, o = g & 1023;
    float m = -FLT_MAX;
    for (int mb = 0; mb < 32; ++mb)
        m = fmaxf(m, partial[((size_t)(b * 32 + mb)) * 1024 + o]);
    out[g] = m + bf[o];
}

// ---------------------------------------------------------------- launch
extern "C" void kernel_launch(void* const* d_in, const int* in_sizes, int n_in,
                              void* d_out, int out_size, void* d_ws, size_t ws_size,
                              hipStream_t stream) {
    const float* x  = (const float*)d_in[0];
    const float* W0 = (const float*)d_in[1];
    const float* b0 = (const float*)d_in[2];
    const float* W1 = (const float*)d_in[3];
    const float* b1 = (const float*)d_in[4];
    const float* W2 = (const float*)d_in[5];
    const float* b2 = (const float*)d_in[6];
    const float* W3 = (const float*)d_in[7];
    const float* b3 = (const float*)d_in[8];
    const float* Wf = (const float*)d_in[9];
    const float* bf = (const float*)d_in[10];
    (void)in_sizes; (void)n_in; (void)out_size; (void)ws_size;

    char* ws = (char*)d_ws;
    size_t off = 0;
    float* feats = (float*)(ws + off); off += (size_t)BN * FSTR * 4;        // 32 MB
    float* sq    = (float*)(ws + off); off += (size_t)BN * 4;               // 64 KB
    int*   idx   = (int*)  (ws + off); off += (size_t)BN * KNN * 4;         // 1.25 MB
    float* GC    = (float*)(ws + off); off += (size_t)BN * 512 * 4;         // 32 MB
    float* partial = GC;               // alias: GC free when final phase runs
    short* hhi   = (short*)(ws + off); off += (size_t)BN * 128 * 2;         // 4 MB
    short* hlo   = (short*)(ws + off); off += (size_t)BN * 128 * 2;         // 4 MB
    short* ebhi  = (short*)(ws + off); off += (size_t)90112 * 2;
    short* eblo  = (short*)(ws + off); off += (size_t)90112 * 2;
    short* wfhi  = (short*)(ws + off); off += (size_t)1024 * 512 * 2;       // 1 MB
    short* wflo  = (short*)(ws + off); off += (size_t)1024 * 512 * 2;       // 1 MB
    float* gram  = (float*)(ws + off); off += (size_t)4 * NP * NP * 4;      // 64 MB
    short* fhi   = (short*)gram;                    // alias: gram dead by final phase
    short* flo   = fhi + (size_t)BN * 512;          // 16 MB + 16 MB inside gram's 64 MB
    short* b1hi = ebhi,         *b1lo = eblo;                               // 128 x 64
    short* b2hi = ebhi + 8192,  *b2lo = eblo + 8192;                        // 256 x 64
    short* b3hi = ebhi + 24576, *b3lo = eblo + 24576;                       // 512 x 128

    // weight preps
    uvprep_kernel<<<16, 256, 0, stream>>>(W1, 64, 64, b1hi, b1lo);
    uvprep_kernel<<<32, 256, 0, stream>>>(W2, 64, 128, b2hi, b2lo);
    uvprep_kernel<<<128, 256, 0, stream>>>(W3, 128, 256, b3hi, b3lo);
    wfprep_kernel<<<2048, 256, 0, stream>>>(Wf, wfhi, wflo);

    // Layer 0: C=3 -> 64 @ feats[0:64]  (fp32 VALU)
    sq_kernel<3><<<BN / 256, 256, 0, stream>>>(x, 3, sq);
    knn_kernel<3><<<BN / 4, 256, 0, stream>>>(x, 3, sq, idx);
    edge_kernel<3, 64, 8><<<BN / 8, 256, 0, stream>>>(x, 3, W0, b0, idx, feats + 0);

    // Layer 1: 64 -> 64 @ feats[64:128]
    sq_kernel<64><<<BN / 256, 256, 0, stream>>>(feats + 0, FSTR, sq);
    hprep_kernel<<<(BN * 64) / 256, 256, 0, stream>>>(feats + 0, FSTR, 64, BN * 64, hhi, hlo);
    for (int grp = 0; grp < 2; ++grp) {
        int g0 = grp * 4 * NP;
        gram_mfma<1><<<dim3(128, 16), 256, 0, stream>>>(hhi, hlo, sq, g0, gram);
        select_topk<<<4 * NP / 8, 512, 0, stream>>>(gram, g0, idx);
    }
    gemm_node<1><<<dim3(BN / 64, 1), 256, 0, stream>>>(hhi, hlo, b1hi, b1lo, 128, GC);
    gather_max<64, 4><<<BN / 4, 256, 0, stream>>>(GC, 128, idx, b1, feats + 64);

    // Layer 2: 64 -> 128 @ feats[128:256]
    sq_kernel<64><<<BN / 256, 256, 0, stream>>>(feats + 64, FSTR, sq);
    hprep_kernel<<<(BN * 64) / 256, 256, 0, stream>>>(feats + 64, FSTR, 64, BN * 64, hhi, hlo);
    for (int grp = 0; grp < 2; ++grp) {
        int g0 = grp * 4 * NP;
        gram_mfma<1><<<dim3(128, 16), 256, 0, stream>>>(hhi, hlo, sq, g0, gram);
        select_topk<<<4 * NP / 8, 512, 0, stream>>>(gram, g0, idx);
    }
    gemm_node<1><<<dim3(BN / 64, 2), 256, 0, stream>>>(hhi, hlo, b2hi, b2lo, 256, GC);
    gather_max<128, 2><<<BN / 2, 256, 0, stream>>>(GC, 256, idx, b2, feats + 128);

    // Layer 3: 128 -> 256 @ feats[256:512]
    sq_kernel<128><<<BN / 256, 256, 0, stream>>>(feats + 128, FSTR, sq);
    hprep_kernel<<<(BN * 128) / 256, 256, 0, stream>>>(feats + 128, FSTR, 128, BN * 128, hhi, hlo);
    for (int grp = 0; grp < 2; ++grp) {
        int g0 = grp * 4 * NP;
        gram_mfma<2><<<dim3(128, 16), 256, 0, stream>>>(hhi, hlo, sq, g0, gram);
        select_topk<<<4 * NP / 8, 512, 0, stream>>>(gram, g0, idx);
    }
    gemm_node<2><<<dim3(BN / 64, 4), 256, 0, stream>>>(hhi, hlo, b3hi, b3lo, 512, GC);
    gather_max<256, 1><<<BN, 256, 0, stream>>>(GC, 512, idx, b3, feats + 256);

    // Final 512 -> 1024 + global max pool (MFMA, direct bf16 planes)
    hprep_kernel<<<(BN * 512) / 256, 256, 0, stream>>>(feats, FSTR, 512, BN * 512, fhi, flo);
    final_mfma<<<dim3(BN / 64, 8), 256, 0, stream>>>(fhi, flo, wfhi, wflo, partial);
    final_reduce<<<32, 256, 0, stream>>>(partial, bf, (float*)d_out);
}

// Round 14
// 801.062 us; speedup vs baseline: 1.2498x; 1.2498x over previous
//
#include <hip/hip_runtime.h>
#include <float.h>

constexpr int NB   = 8;      // batches
constexpr int NP   = 2048;   // points per batch
constexpr int BN   = NB * NP;
constexpr int KNN  = 20;     // neighbors
constexpr int FSTR = 512;    // feats row stride (64+64+128+256)

typedef short short8 __attribute__((ext_vector_type(8)));
typedef float f32x4  __attribute__((ext_vector_type(4)));

__device__ __forceinline__ unsigned f2bf_rne(float x) {
    unsigned u = __float_as_uint(x);
    unsigned r = (u >> 16) & 1;
    return (u + 0x7fffu + r) >> 16;
}
__device__ __forceinline__ float bf2f(unsigned h) { return __uint_as_float(h << 16); }

// ---------------------------------------------------------------- sq = |h|^2
template<int C>
__global__ __launch_bounds__(256) void sq_kernel(const float* __restrict__ h,
                                                 int istr,
                                                 float* __restrict__ sq) {
    int i = blockIdx.x * 256 + threadIdx.x;
    if (i >= BN) return;
    const float* p = h + (size_t)i * istr;
    float s = 0.f;
    #pragma unroll
    for (int c = 0; c < C; ++c) { float v = p[c]; s += v * v; }
    sq[i] = s;
}

// ---------------------------------------------------------------- kNN top-20 (C=3 path)
template<int C>
__global__ __launch_bounds__(256) void knn_kernel(const float* __restrict__ h,
                                                  int istr,
                                                  const float* __restrict__ sq,
                                                  int* __restrict__ knn_idx) {
    constexpr int GI = 4;
    __shared__ float negd[GI][NP];          // 32 KB
    const int t    = threadIdx.x;
    const int r0   = blockIdx.x * GI;
    const int base = (r0 >> 11) << 11;

    float hi[GI][3], sqi[GI];
    #pragma unroll
    for (int g = 0; g < GI; ++g) {
        const float* p = h + (size_t)(r0 + g) * istr;
        hi[g][0] = p[0]; hi[g][1] = p[1]; hi[g][2] = p[2];
        sqi[g] = sq[r0 + g];
    }
    for (int j = t; j < NP; j += 256) {
        const float* pj = h + (size_t)(base + j) * istr;
        float x0 = pj[0], x1 = pj[1], x2 = pj[2];
        float sqj = sq[base + j];
        #pragma unroll
        for (int g = 0; g < GI; ++g) {
            float d = hi[g][0]*x0 + hi[g][1]*x1 + hi[g][2]*x2;
            negd[g][j] = 2.f * d - sqi[g] - sqj;
        }
    }
    __syncthreads();

    const int w = t >> 6;
    const int l = t & 63;
    const float* row = &negd[w][0];
    float v[32];
    #pragma unroll
    for (int u = 0; u < 32; ++u) v[u] = row[l + 64 * u];
    float m0 = v[0], m1 = v[16];
    int   u0 = 0,    u1 = 16;
    #pragma unroll
    for (int u = 1; u < 16; ++u)  { if (v[u] > m0) { m0 = v[u]; u0 = u; } }
    #pragma unroll
    for (int u = 17; u < 32; ++u) { if (v[u] > m1) { m1 = v[u]; u1 = u; } }

    int* out = knn_idx + (size_t)(r0 + w) * KNN;
    for (int it = 0; it < KNN; ++it) {
        float bv; int bu;
        if (m0 >= m1) { bv = m0; bu = u0; } else { bv = m1; bu = u1; }
        int bj = l + (bu << 6);
        #pragma unroll
        for (int off = 1; off < 64; off <<= 1) {
            float ov = __shfl_xor(bv, off);
            int   oj = __shfl_xor(bj, off);
            if (ov > bv || (ov == bv && oj < bj)) { bv = ov; bj = oj; }
        }
        if (l == 0) out[it] = bj;
        const int  ur  = bj >> 6;
        const bool own = ((bj & 63) == l);
        if (ur < 16) {
            #pragma unroll
            for (int u = 0; u < 16; ++u)
                if (own && u == ur) v[u] = -FLT_MAX;
            m0 = v[0]; u0 = 0;
            #pragma unroll
            for (int u = 1; u < 16; ++u) if (v[u] > m0) { m0 = v[u]; u0 = u; }
        } else {
            #pragma unroll
            for (int u = 16; u < 32; ++u)
                if (own && u == ur) v[u] = -FLT_MAX;
            m1 = v[16]; u1 = 16;
            #pragma unroll
            for (int u = 17; u < 32; ++u) if (v[u] > m1) { m1 = v[u]; u1 = u; }
        }
    }
}

// ---------------------------------------------------------------- H hi/lo plane prep
__global__ __launch_bounds__(256) void hprep_kernel(const float* __restrict__ h, int istr,
                                                    int cin, int total,
                                                    short* __restrict__ hhi,
                                                    short* __restrict__ hlo) {
    int e = blockIdx.x * 256 + threadIdx.x;
    if (e >= total) return;
    int r = e / cin, c = e - r * cin;
    float v = h[(size_t)r * istr + c];
    unsigned hh = f2bf_rne(v);
    unsigned ll = __float_as_uint(v - bf2f(hh)) >> 16;
    hhi[e] = (short)hh;
    hlo[e] = (short)ll;
}

// ================================================================ shared A-staging macro body
// Stage 64x64 bf16 hi/lo A-tile (rows arow0.., k-cols kc*64..) from global planes
// into XOR-swizzled LDS. Ab = char* LDS base; PLANE = 64*64*2 bytes.

// ---------------------------------------------------------------- Gram via MFMA (bf16 hi/lo, 3-term, LDS-staged A from planes)
template<int KC>    // K = KC*64 = C
__global__ __launch_bounds__(256) void gram_mfma(const short* __restrict__ hhi,
                                                 const short* __restrict__ hlo,
                                                 const float* __restrict__ sq,
                                                 int g0,
                                                 float* __restrict__ gram) {
    constexpr int C = KC * 64;
    constexpr int PLANE = 64 * 64 * 2;
    __shared__ short A[2 * 64 * 64];               // 16 KB
    const int t   = threadIdx.x;
    const int bx  = blockIdx.x;
    const int ct  = blockIdx.y;
    const int big = bx >> 5, rt = bx & 31;
    const int bbase = g0 + big * NP;               // batch base (global row)
    const int row0g = bbase + rt * 64;
    const int l = t & 63, w = t >> 6, g = l >> 4, cl = l & 15;

    f32x4 acc[4][2];
    #pragma unroll
    for (int mt = 0; mt < 4; ++mt)
        #pragma unroll
        for (int nt = 0; nt < 2; ++nt)
            acc[mt][nt] = (f32x4){0.f, 0.f, 0.f, 0.f};

    char* Ab = (char*)A;
    #pragma unroll 1
    for (int kc = 0; kc < KC; ++kc) {
        for (int u = t; u < 512; u += 256) {       // 64 rows x 8 short8-chunks
            int row = u >> 3, c8 = u & 7;
            size_t goff = (size_t)(row0g + row) * C + kc * 64 + c8 * 8;
            short8 vh = *(const short8*)(hhi + goff);
            short8 vl = *(const short8*)(hlo + goff);
            int byte = (row * 128 + c8 * 16) ^ ((row & 7) << 4);
            *(short8*)(Ab + byte)         = vh;
            *(short8*)(Ab + PLANE + byte) = vl;
        }
        __syncthreads();

        #pragma unroll
        for (int ks = 0; ks < 2; ++ks) {
            const int k0 = kc * 64 + ks * 32 + g * 8;
            short8 ah[4], al[4], bh[2], bl[2];
            #pragma unroll
            for (int mt = 0; mt < 4; ++mt) {
                int row  = mt * 16 + cl;
                int byte = (row * 128 + (ks * 32 + g * 8) * 2) ^ ((row & 7) << 4);
                ah[mt] = *(const short8*)(Ab + byte);
                al[mt] = *(const short8*)(Ab + PLANE + byte);
            }
            #pragma unroll
            for (int nt = 0; nt < 2; ++nt) {
                int col = ct * 128 + (w * 2 + nt) * 16 + cl;
                size_t boff = (size_t)(bbase + col) * C + k0;
                bh[nt] = *(const short8*)(hhi + boff);
                bl[nt] = *(const short8*)(hlo + boff);
            }
            #pragma unroll
            for (int mt = 0; mt < 4; ++mt)
                #pragma unroll
                for (int nt = 0; nt < 2; ++nt) {
                    acc[mt][nt] = __builtin_amdgcn_mfma_f32_16x16x32_bf16(
                        ah[mt], bh[nt], acc[mt][nt], 0, 0, 0);
                    acc[mt][nt] = __builtin_amdgcn_mfma_f32_16x16x32_bf16(
                        ah[mt], bl[nt], acc[mt][nt], 0, 0, 0);
                    acc[mt][nt] = __builtin_amdgcn_mfma_f32_16x16x32_bf16(
                        al[mt], bh[nt], acc[mt][nt], 0, 0, 0);
                }
        }
        __syncthreads();
    }

    // epilogue: negd = 2*acc - sq_r - sq_c
    #pragma unroll
    for (int nt = 0; nt < 2; ++nt) {
        int col = ct * 128 + (w * 2 + nt) * 16 + cl;
        float sqc = sq[bbase + col];
        #pragma unroll
        for (int mt = 0; mt < 4; ++mt) {
            #pragma unroll
            for (int j = 0; j < 4; ++j) {
                int rl = rt * 64 + mt * 16 + g * 4 + j;
                float val = 2.f * acc[mt][nt][j] - sq[bbase + rl] - sqc;
                gram[(size_t)(big * NP + rl) * NP + col] = val;
            }
        }
    }
}

// ---------------------------------------------------------------- top-20 selection from gram rows
__global__ __launch_bounds__(512) void select_topk(const float* __restrict__ gram,
                                                   int g0,
                                                   int* __restrict__ knn_idx) {
    const int t = threadIdx.x, w = t >> 6, l = t & 63;
    const int rlocal = blockIdx.x * 8 + w;
    const float* row = gram + (size_t)rlocal * NP;

    float v[32];
    #pragma unroll
    for (int u = 0; u < 32; ++u) v[u] = row[l + 64 * u];
    float m0 = v[0], m1 = v[16];
    int   u0 = 0,    u1 = 16;
    #pragma unroll
    for (int u = 1; u < 16; ++u)  { if (v[u] > m0) { m0 = v[u]; u0 = u; } }
    #pragma unroll
    for (int u = 17; u < 32; ++u) { if (v[u] > m1) { m1 = v[u]; u1 = u; } }

    int* out = knn_idx + (size_t)(g0 + rlocal) * KNN;
    for (int it = 0; it < KNN; ++it) {
        float bv; int bu;
        if (m0 >= m1) { bv = m0; bu = u0; } else { bv = m1; bu = u1; }
        int bj = l + (bu << 6);
        #pragma unroll
        for (int off = 1; off < 64; off <<= 1) {
            float ov = __shfl_xor(bv, off);
            int   oj = __shfl_xor(bj, off);
            if (ov > bv || (ov == bv && oj < bj)) { bv = ov; bj = oj; }
        }
        if (l == 0) out[it] = bj;
        const int  ur  = bj >> 6;
        const bool own = ((bj & 63) == l);
        if (ur < 16) {
            #pragma unroll
            for (int u = 0; u < 16; ++u)
                if (own && u == ur) v[u] = -FLT_MAX;
            m0 = v[0]; u0 = 0;
            #pragma unroll
            for (int u = 1; u < 16; ++u) if (v[u] > m0) { m0 = v[u]; u0 = u; }
        } else {
            #pragma unroll
            for (int u = 16; u < 32; ++u)
                if (own && u == ur) v[u] = -FLT_MAX;
            m1 = v[16]; u1 = 16;
            #pragma unroll
            for (int u = 17; u < 32; ++u) if (v[u] > m1) { m1 = v[u]; u1 = u; }
        }
    }
}

// ---------------------------------------------------------------- U/V' hi-lo prep
__global__ __launch_bounds__(256) void uvprep_kernel(const float* __restrict__ W,
                                                     int cin, int cout,
                                                     short* __restrict__ bhi,
                                                     short* __restrict__ blo) {
    int e = blockIdx.x * 256 + threadIdx.x;
    if (e >= cout * cin) return;
    int o = e / cin, c = e - o * cin;
    float u  = W[(size_t)o * (2 * cin) + c];
    float vv = W[(size_t)o * (2 * cin) + cin + c];
    float vp = vv - u;
    unsigned hu = f2bf_rne(u);
    unsigned lu = __float_as_uint(u - bf2f(hu)) >> 16;
    unsigned hv = f2bf_rne(vp);
    unsigned lv = __float_as_uint(vp - bf2f(hv)) >> 16;
    bhi[(size_t)o * cin + c] = (short)hu;
    blo[(size_t)o * cin + c] = (short)lu;
    bhi[(size_t)(cout + o) * cin + c] = (short)hv;
    blo[(size_t)(cout + o) * cin + c] = (short)lv;
}

// ---------------------------------------------------------------- Wf hi/lo prep (flat)
__global__ __launch_bounds__(256) void wfprep_kernel(const float* __restrict__ Wf,
                                                     short* __restrict__ whi,
                                                     short* __restrict__ wlo) {
    int e = blockIdx.x * 256 + threadIdx.x;
    float v = Wf[e];
    unsigned h = f2bf_rne(v);
    unsigned lo = __float_as_uint(v - bf2f(h)) >> 16;
    whi[e] = (short)h;
    wlo[e] = (short)lo;
}

// ---------------------------------------------------------------- node GEMM via MFMA (bf16 hi/lo, 3-term, LDS-staged A from planes)
template<int KC>
__global__ __launch_bounds__(256) void gemm_node(const short* __restrict__ ahi,
                                                 const short* __restrict__ alo,
                                                 const short* __restrict__ bhi_,
                                                 const short* __restrict__ blo_,
                                                 int nstr,
                                                 float* __restrict__ out) {
    constexpr int C = KC * 64;
    constexpr int PLANE = 64 * 64 * 2;
    __shared__ short A[2 * 64 * 64];
    const int t    = threadIdx.x;
    const int mb   = blockIdx.x;
    const int ny   = blockIdx.y;
    const int row0 = mb * 64;
    const int l = t & 63, w = t >> 6, g = l >> 4, cl = l & 15;

    f32x4 acc[4][2];
    #pragma unroll
    for (int mt = 0; mt < 4; ++mt)
        #pragma unroll
        for (int nt = 0; nt < 2; ++nt)
            acc[mt][nt] = (f32x4){0.f, 0.f, 0.f, 0.f};

    char* Ab = (char*)A;
    #pragma unroll 1
    for (int kc = 0; kc < KC; ++kc) {
        for (int u = t; u < 512; u += 256) {
            int row = u >> 3, c8 = u & 7;
            size_t goff = (size_t)(row0 + row) * C + kc * 64 + c8 * 8;
            short8 vh = *(const short8*)(ahi + goff);
            short8 vl = *(const short8*)(alo + goff);
            int byte = (row * 128 + c8 * 16) ^ ((row & 7) << 4);
            *(short8*)(Ab + byte)         = vh;
            *(short8*)(Ab + PLANE + byte) = vl;
        }
        __syncthreads();

        #pragma unroll
        for (int ks = 0; ks < 2; ++ks) {
            const int k0 = kc * 64 + ks * 32 + g * 8;
            short8 ah[4], al[4], bh[2], bl[2];
            #pragma unroll
            for (int mt = 0; mt < 4; ++mt) {
                int row  = mt * 16 + cl;
                int byte = (row * 128 + (ks * 32 + g * 8) * 2) ^ ((row & 7) << 4);
                ah[mt] = *(const short8*)(Ab + byte);
                al[mt] = *(const short8*)(Ab + PLANE + byte);
            }
            #pragma unroll
            for (int nt = 0; nt < 2; ++nt) {
                int o = ny * 128 + (w * 2 + nt) * 16 + cl;
                size_t boff = (size_t)o * C + k0;
                bh[nt] = *(const short8*)(bhi_ + boff);
                bl[nt] = *(const short8*)(blo_ + boff);
            }
            #pragma unroll
            for (int mt = 0; mt < 4; ++mt)
                #pragma unroll
                for (int nt = 0; nt < 2; ++nt) {
                    acc[mt][nt] = __builtin_amdgcn_mfma_f32_16x16x32_bf16(
                        ah[mt], bh[nt], acc[mt][nt], 0, 0, 0);
                    acc[mt][nt] = __builtin_amdgcn_mfma_f32_16x16x32_bf16(
                        ah[mt], bl[nt], acc[mt][nt], 0, 0, 0);
                    acc[mt][nt] = __builtin_amdgcn_mfma_f32_16x16x32_bf16(
                        al[mt], bh[nt], acc[mt][nt], 0, 0, 0);
                }
        }
        __syncthreads();
    }

    #pragma unroll
    for (int nt = 0; nt < 2; ++nt) {
        int col = ny * 128 + (w * 2 + nt) * 16 + cl;
        #pragma unroll
        for (int mt = 0; mt < 4; ++mt) {
            #pragma unroll
            for (int j = 0; j < 4; ++j) {
                int row = row0 + mt * 16 + g * 4 + j;
                out[(size_t)row * nstr + col] = acc[mt][nt][j];
            }
        }
    }
}

// ---------------------------------------------------------------- gather-max epilogue
template<int COUT, int PPB>
__global__ __launch_bounds__(256) void gather_max(const float* __restrict__ GC, int nstr,
                                                  const int* __restrict__ knn_idx,
                                                  const float* __restrict__ bias,
                                                  float* __restrict__ hout) {
    static_assert(COUT * PPB == 256, "block 256");
    const int t  = threadIdx.x;
    const int pl = t / COUT;
    const int o  = t - pl * COUT;
    const int p  = blockIdx.x * PPB + pl;
    const int base = (p >> 11) << 11;
    const int* jrow = knn_idx + (size_t)p * KNN;

    float mx = -FLT_MAX;
    #pragma unroll
    for (int k = 0; k < KNN; ++k) {
        int j = jrow[k];
        mx = fmaxf(mx, GC[(size_t)(base + j) * nstr + o]);
    }
    float val = mx + GC[(size_t)p * nstr + COUT + o] + bias[o];
    val = val > 0.f ? val : 0.2f * val;
    hout[(size_t)p * FSTR + o] = val;
}

// ---------------------------------------------------------------- EdgeConv L0 (CIN=3, fp32 VALU)
template<int CIN, int COUT, int PPB>
__global__ __launch_bounds__(256) void edge_kernel(const float* __restrict__ hin,
                                                   int istr,
                                                   const float* __restrict__ W,
                                                   const float* __restrict__ bias,
                                                   const int* __restrict__ knn_idx,
                                                   float* __restrict__ hout) {
    constexpr int TPP = COUT / 2;
    static_assert(PPB * TPP == 256, "block must be 256 threads");
    __shared__ float diff[PPB][KNN][CIN];
    __shared__ float hi[PPB][CIN];
    __shared__ int   nj[PPB][KNN];

    const int t    = threadIdx.x;
    const int r0   = blockIdx.x * PPB;
    const int base = (r0 >> 11) << 11;

    for (int e = t; e < PPB * KNN; e += 256) {
        int p = e / KNN, kk = e - p * KNN;
        nj[p][kk] = knn_idx[(size_t)(r0 + p) * KNN + kk];
    }
    for (int e = t; e < PPB * CIN; e += 256) {
        int p = e / CIN, c = e - p * CIN;
        hi[p][c] = hin[(size_t)(r0 + p) * istr + c];
    }
    __syncthreads();
    for (int e = t; e < PPB * KNN * CIN; e += 256) {
        int p  = e / (KNN * CIN);
        int rm = e - p * (KNN * CIN);
        int kk = rm / CIN, c = rm - kk * CIN;
        diff[p][kk][c] = hin[(size_t)(base + nj[p][kk]) * istr + c] - hi[p][c];
    }
    __syncthreads();

    const int p  = t / TPP;
    const int oo = t - p * TPP;
    const float* W0 = W + (size_t)oo * (2 * CIN);
    const float* W1 = W + (size_t)(oo + TPP) * (2 * CIN);

    float ctr0 = bias[oo], ctr1 = bias[oo + TPP];
    float acc[2][KNN];
    #pragma unroll
    for (int kk = 0; kk < KNN; ++kk) { acc[0][kk] = 0.f; acc[1][kk] = 0.f; }

    for (int c = 0; c < CIN; ++c) {
        float hv = hi[p][c];
        ctr0 += W0[CIN + c] * hv;
        ctr1 += W1[CIN + c] * hv;
    }
    for (int c = 0; c < CIN; ++c) {
        float w0 = W0[c], w1 = W1[c];
        #pragma unroll
        for (int kk = 0; kk < KNN; ++kk) {
            float d = diff[p][kk][c];
            acc[0][kk] += w0 * d;
            acc[1][kk] += w1 * d;
        }
    }

    float m0 = -FLT_MAX, m1 = -FLT_MAX;
    #pragma unroll
    for (int kk = 0; kk < KNN; ++kk) {
        m0 = fmaxf(m0, acc[0][kk] + ctr0);
        m1 = fmaxf(m1, acc[1][kk] + ctr1);
    }
    float r0v = m0 > 0.f ? m0 : 0.2f * m0;
    float r1v = m1 > 0.f ? m1 : 0.2f * m1;
    hout[(size_t)(r0 + p) * FSTR + oo]       = r0v;
    hout[(size_t)(r0 + p) * FSTR + oo + TPP] = r1v;
}

// ---------------------------------------------------------------- final GEMM via MFMA (bf16 hi/lo, 3-term, LDS-staged A from planes) + col-max
__global__ __launch_bounds__(256) void final_mfma(const short* __restrict__ fhi,
                                                  const short* __restrict__ flo,
                                                  const short* __restrict__ wfhi,
                                                  const short* __restrict__ wflo,
                                                  float* __restrict__ partial) {
    constexpr int PLANE = 64 * 64 * 2;
    __shared__ short A[2 * 64 * 64];
    const int t    = threadIdx.x;
    const int mb   = blockIdx.x;
    const int ny   = blockIdx.y;
    const int row0 = mb * 64;
    const int l = t & 63, w = t >> 6, g = l >> 4, cl = l & 15;

    f32x4 acc[4][2];
    #pragma unroll
    for (int mt = 0; mt < 4; ++mt)
        #pragma unroll
        for (int nt = 0; nt < 2; ++nt)
            acc[mt][nt] = (f32x4){0.f, 0.f, 0.f, 0.f};

    char* Ab = (char*)A;
    #pragma unroll 1
    for (int kc = 0; kc < 8; ++kc) {
        for (int u = t; u < 512; u += 256) {
            int row = u >> 3, c8 = u & 7;
            size_t goff = (size_t)(row0 + row) * 512 + kc * 64 + c8 * 8;
            short8 vh = *(const short8*)(fhi + goff);
            short8 vl = *(const short8*)(flo + goff);
            int byte = (row * 128 + c8 * 16) ^ ((row & 7) << 4);
            *(short8*)(Ab + byte)         = vh;
            *(short8*)(Ab + PLANE + byte) = vl;
        }
        __syncthreads();

        #pragma unroll
        for (int ks = 0; ks < 2; ++ks) {
            const int k0 = kc * 64 + ks * 32 + g * 8;
            short8 ah[4], al[4], bh[2], bl[2];
            #pragma unroll
            for (int mt = 0; mt < 4; ++mt) {
                int row  = mt * 16 + cl;
                int byte = (row * 128 + (ks * 32 + g * 8) * 2) ^ ((row & 7) << 4);
                ah[mt] = *(const short8*)(Ab + byte);
                al[mt] = *(const short8*)(Ab + PLANE + byte);
            }
            #pragma unroll
            for (int nt = 0; nt < 2; ++nt) {
                int o = ny * 128 + (w * 2 + nt) * 16 + cl;
                size_t boff = (size_t)o * 512 + k0;
                bh[nt] = *(const short8*)(wfhi + boff);
                bl[nt] = *(const short8*)(wflo + boff);
            }
            #pragma unroll
            for (int mt = 0; mt < 4; ++mt)
                #pragma unroll
                for (int nt = 0; nt < 2; ++nt) {
                    acc[mt][nt] = __builtin_amdgcn_mfma_f32_16x16x32_bf16(
                        ah[mt], bh[nt], acc[mt][nt], 0, 0, 0);
                    acc[mt][nt] = __builtin_amdgcn_mfma_f32_16x16x32_bf16(
                        ah[mt], bl[nt], acc[mt][nt], 0, 0, 0);
                    acc[mt][nt] = __builtin_amdgcn_mfma_f32_16x16x32_bf16(
                        al[mt], bh[nt], acc[mt][nt], 0, 0, 0);
                }
        }
        __syncthreads();
    }

    #pragma unroll
    for (int nt = 0; nt < 2; ++nt) {
        float pm = -FLT_MAX;
        #pragma unroll
        for (int mt = 0; mt < 4; ++mt) {
            f32x4 v = acc[mt][nt];
            pm = fmaxf(pm, fmaxf(fmaxf(v[0], v[1]), fmaxf(v[2], v[3])));
        }
        pm = fmaxf(pm, __shfl_xor(pm, 16));
        pm = fmaxf(pm, __shfl_xor(pm, 32));
        if (g == 0) {
            int col = ny * 128 + (w * 2 + nt) * 16 + cl;
            partial[(size_t)mb * 1024 + col] = pm;
        }
    }
}

__global__ __launch_bounds__(256) void final_reduce(const float* __restrict__ partial,
                                                    const float* __restrict__ bf,
                                                    float* __restrict__ out) {
    int g = blockIdx.x * 256 + threadIdx.x;
    int b = g >> 10, o = g & 1023;
    float m = -FLT_MAX;
    for (int mb = 0; mb < 32; ++mb)
        m = fmaxf(m, partial[((size_t)(b * 32 + mb)) * 1024 + o]);
    out[g] = m + bf[o];
}

// ---------------------------------------------------------------- launch
extern "C" void kernel_launch(void* const* d_in, const int* in_sizes, int n_in,
                              void* d_out, int out_size, void* d_ws, size_t ws_size,
                              hipStream_t stream) {
    const float* x  = (const float*)d_in[0];
    const float* W0 = (const float*)d_in[1];
    const float* b0 = (const float*)d_in[2];
    const float* W1 = (const float*)d_in[3];
    const float* b1 = (const float*)d_in[4];
    const float* W2 = (const float*)d_in[5];
    const float* b2 = (const float*)d_in[6];
    const float* W3 = (const float*)d_in[7];
    const float* b3 = (const float*)d_in[8];
    const float* Wf = (const float*)d_in[9];
    const float* bf = (const float*)d_in[10];
    (void)in_sizes; (void)n_in; (void)out_size; (void)ws_size;

    char* ws = (char*)d_ws;
    size_t off = 0;
    float* feats = (float*)(ws + off); off += (size_t)BN * FSTR * 4;        // 32 MB
    float* sq    = (float*)(ws + off); off += (size_t)BN * 4;               // 64 KB
    int*   idx   = (int*)  (ws + off); off += (size_t)BN * KNN * 4;         // 1.25 MB
    float* GC    = (float*)(ws + off); off += (size_t)BN * 512 * 4;         // 32 MB
    float* partial = GC;               // alias: GC free when final phase runs
    short* hhi   = (short*)(ws + off); off += (size_t)BN * 128 * 2;         // 4 MB
    short* hlo   = (short*)(ws + off); off += (size_t)BN * 128 * 2;         // 4 MB
    short* ebhi  = (short*)(ws + off); off += (size_t)90112 * 2;
    short* eblo  = (short*)(ws + off); off += (size_t)90112 * 2;
    short* wfhi  = (short*)(ws + off); off += (size_t)1024 * 512 * 2;       // 1 MB
    short* wflo  = (short*)(ws + off); off += (size_t)1024 * 512 * 2;       // 1 MB
    float* gram  = (float*)(ws + off); off += (size_t)4 * NP * NP * 4;      // 64 MB
    short* fhi   = (short*)gram;                    // alias: gram dead by final phase
    short* flo   = fhi + (size_t)BN * 512;          // 16 MB + 16 MB inside gram's 64 MB
    short* b1hi = ebhi,         *b1lo = eblo;                               // 128 x 64
    short* b2hi = ebhi + 8192,  *b2lo = eblo + 8192;                        // 256 x 64
    short* b3hi = ebhi + 24576, *b3lo = eblo + 24576;                       // 512 x 128

    // weight preps
    uvprep_kernel<<<16, 256, 0, stream>>>(W1, 64, 64, b1hi, b1lo);
    uvprep_kernel<<<32, 256, 0, stream>>>(W2, 64, 128, b2hi, b2lo);
    uvprep_kernel<<<128, 256, 0, stream>>>(W3, 128, 256, b3hi, b3lo);
    wfprep_kernel<<<2048, 256, 0, stream>>>(Wf, wfhi, wflo);

    // Layer 0: C=3 -> 64 @ feats[0:64]  (fp32 VALU)
    sq_kernel<3><<<BN / 256, 256, 0, stream>>>(x, 3, sq);
    knn_kernel<3><<<BN / 4, 256, 0, stream>>>(x, 3, sq, idx);
    edge_kernel<3, 64, 8><<<BN / 8, 256, 0, stream>>>(x, 3, W0, b0, idx, feats + 0);

    // Layer 1: 64 -> 64 @ feats[64:128]
    sq_kernel<64><<<BN / 256, 256, 0, stream>>>(feats + 0, FSTR, sq);
    hprep_kernel<<<(BN * 64) / 256, 256, 0, stream>>>(feats + 0, FSTR, 64, BN * 64, hhi, hlo);
    for (int grp = 0; grp < 2; ++grp) {
        int g0 = grp * 4 * NP;
        gram_mfma<1><<<dim3(128, 16), 256, 0, stream>>>(hhi, hlo, sq, g0, gram);
        select_topk<<<4 * NP / 8, 512, 0, stream>>>(gram, g0, idx);
    }
    gemm_node<1><<<dim3(BN / 64, 1), 256, 0, stream>>>(hhi, hlo, b1hi, b1lo, 128, GC);
    gather_max<64, 4><<<BN / 4, 256, 0, stream>>>(GC, 128, idx, b1, feats + 64);

    // Layer 2: 64 -> 128 @ feats[128:256]
    sq_kernel<64><<<BN / 256, 256, 0, stream>>>(feats + 64, FSTR, sq);
    hprep_kernel<<<(BN * 64) / 256, 256, 0, stream>>>(feats + 64, FSTR, 64, BN * 64, hhi, hlo);
    for (int grp = 0; grp < 2; ++grp) {
        int g0 = grp * 4 * NP;
        gram_mfma<1><<<dim3(128, 16), 256, 0, stream>>>(hhi, hlo, sq, g0, gram);
        select_topk<<<4 * NP / 8, 512, 0, stream>>>(gram, g0, idx);
    }
    gemm_node<1><<<dim3(BN / 64, 2), 256, 0, stream>>>(hhi, hlo, b2hi, b2lo, 256, GC);
    gather_max<128, 2><<<BN / 2, 256, 0, stream>>>(GC, 256, idx, b2, feats + 128);

    // Layer 3: 128 -> 256 @ feats[256:512]
    sq_kernel<128><<<BN / 256, 256, 0, stream>>>(feats + 128, FSTR, sq);
    hprep_kernel<<<(BN * 128) / 256, 256, 0, stream>>>(feats + 128, FSTR, 128, BN * 128, hhi, hlo);
    for (int grp = 0; grp < 2; ++grp) {
        int g0 = grp * 4 * NP;
        gram_mfma<2><<<dim3(128, 16), 256, 0, stream>>>(hhi, hlo, sq, g0, gram);
        select_topk<<<4 * NP / 8, 512, 0, stream>>>(gram, g0, idx);
    }
    gemm_node<2><<<dim3(BN / 64, 4), 256, 0, stream>>>(hhi, hlo, b3hi, b3lo, 512, GC);
    gather_max<256, 1><<<BN, 256, 0, stream>>>(GC, 512, idx, b3, feats + 256);

    // Final 512 -> 1024 + global max pool (MFMA, LDS-staged from bf16 planes)
    hprep_kernel<<<(BN * 512) / 256, 256, 0, stream>>>(feats, FSTR, 512, BN * 512, fhi, flo);
    final_mfma<<<dim3(BN / 64, 8), 256, 0, stream>>>(fhi, flo, wfhi, wflo, partial);
    final_reduce<<<32, 256, 0, stream>>>(partial, bf, (float*)d_out);
}